// Round 5
// baseline (279.002 us; speedup 1.0000x reference)
//
#include <hip/hip_runtime.h>
#include <hip/hip_bf16.h>

typedef __attribute__((ext_vector_type(8))) short short8;
typedef __attribute__((ext_vector_type(4))) float f32x4;
typedef __attribute__((ext_vector_type(16))) float f32x16;
typedef __attribute__((ext_vector_type(4))) unsigned short u16x4;

#define D_MODEL 1024
#define N_HEAD 16
#define HEAD_DIM 64
#define T_SEQ 2048
#define BATCH 2
#define M_TOK (BATCH * T_SEQ) /* 4096 */
#define QKV_STRIDE ((size_t)M_TOK * D_MODEL) /* elems per Q/K/V buffer */

__device__ __forceinline__ unsigned short f2bf(float f) {
    union { float f; unsigned u; } v; v.f = f;
    unsigned r = (v.u + 0x7fffu + ((v.u >> 16) & 1u)) >> 16;  // RNE
    return (unsigned short)r;
}

__device__ __forceinline__ void load16_lds(const unsigned short* g, unsigned short* l) {
    __builtin_amdgcn_global_load_lds(
        (const __attribute__((address_space(1))) unsigned int*)(g),
        (__attribute__((address_space(3))) unsigned int*)(l),
        16, 0, 0);
}

// ---------------- cast x (f32 -> bf16), vectorized ----------------
__global__ __launch_bounds__(256) void cast_x(const float* __restrict__ in,
                                              unsigned short* __restrict__ out, int n4) {
    int i = blockIdx.x * 256 + threadIdx.x;
    if (i < n4) {
        float4 v = ((const float4*)in)[i];
        u16x4 o;
        o.x = f2bf(v.x); o.y = f2bf(v.y); o.z = f2bf(v.z); o.w = f2bf(v.w);
        ((u16x4*)out)[i] = o;
    }
}

// ---------------- transpose + cast all 4 weights [1024][1024] f32 -> bf16 T ----------------
__global__ __launch_bounds__(256) void transpose_cast4(
    const float* __restrict__ w0, const float* __restrict__ w1,
    const float* __restrict__ w2, const float* __restrict__ w3,
    unsigned short* __restrict__ o0, unsigned short* __restrict__ o1,
    unsigned short* __restrict__ o2, unsigned short* __restrict__ o3)
{
    __shared__ float tile[32][33];
    const float* in; unsigned short* outT;
    switch (blockIdx.z) {
        case 0: in = w0; outT = o0; break;
        case 1: in = w1; outT = o1; break;
        case 2: in = w2; outT = o2; break;
        default: in = w3; outT = o3; break;
    }
    const int R = 1024, C = 1024;
    const int r0 = blockIdx.x * 32, c0 = blockIdx.y * 32;
    const int tx = threadIdx.x & 31, ty = threadIdx.x >> 5;  // ty 0..7
    #pragma unroll
    for (int jj = 0; jj < 32; jj += 8)
        tile[ty + jj][tx] = in[(size_t)(r0 + ty + jj) * C + c0 + tx];
    __syncthreads();
    #pragma unroll
    for (int jj = 0; jj < 32; jj += 8)
        outT[(size_t)(c0 + ty + jj) * R + r0 + tx] = f2bf(tile[tx][ty + jj]);
}

// ---------------- m97-structure GEMM: C[M,N] = A[M,K] * Bt[N,K]^T ----------------
// mode 1: scatter into QKV buffers: Q raw [B,H,T,Dh]; K scaled by 0.125 [B,H,T,Dh];
//         V transposed [B,H,Dh,T]. outp = base of Q; K at +QKV_STRIDE, V at +2*QKV_STRIDE.
// mode 2: f32 out[M,N] + bias[n]
#define BM 128
#define BN 128
#define BK 32
__global__ __launch_bounds__(256) void gemm_bf16(
    const unsigned short* __restrict__ A,
    const unsigned short* __restrict__ Bt,
    void* __restrict__ outp,
    const float* __restrict__ bias,
    int M, int N, int K, int mode)
{
    __shared__ unsigned short lds_a[BM * BK];  // 8 KiB
    __shared__ unsigned short lds_b[BN * BK];  // 8 KiB
    const int tid = threadIdx.x;
    const int w = tid >> 6, l = tid & 63, lo = l & 15, hi = l >> 4;
    const int wm = w >> 1, wn = w & 1;
    const size_t arow0 = (size_t)blockIdx.x * BM;
    const size_t brow0 = (size_t)blockIdx.y * BN;

    f32x4 acc[4][4];
    #pragma unroll
    for (int i = 0; i < 4; ++i)
        #pragma unroll
        for (int j = 0; j < 4; ++j)
            acc[i][j] = (f32x4){0.f, 0.f, 0.f, 0.f};

    const int ch0 = tid, ch1 = 256 + tid;
    const int r0c = ch0 >> 2, c0c = (ch0 & 3) * 8;
    const int r1c = ch1 >> 2, c1c = (ch1 & 3) * 8;
    const unsigned short* Ab0 = A + (arow0 + r0c) * K + c0c;
    const unsigned short* Ab1 = A + (arow0 + r1c) * K + c1c;
    const unsigned short* Bb0 = Bt + (brow0 + r0c) * K + c0c;
    const unsigned short* Bb1 = Bt + (brow0 + r1c) * K + c1c;
    unsigned short* la0 = lds_a + (size_t)(0 * 256 + w * 64) * 8;
    unsigned short* la1 = lds_a + (size_t)(1 * 256 + w * 64) * 8;
    unsigned short* lb0 = lds_b + (size_t)(0 * 256 + w * 64) * 8;
    unsigned short* lb1 = lds_b + (size_t)(1 * 256 + w * 64) * 8;

    for (int k0 = 0; k0 < K; k0 += BK) {
        load16_lds(Ab0 + k0, la0);
        load16_lds(Ab1 + k0, la1);
        load16_lds(Bb0 + k0, lb0);
        load16_lds(Bb1 + k0, lb1);
        __syncthreads();
        short8 af[4], bfr[4];
        #pragma unroll
        for (int i = 0; i < 4; ++i)
            af[i] = *(const short8*)(lds_a + (wm * 64 + i * 16 + lo) * BK + 8 * hi);
        #pragma unroll
        for (int j = 0; j < 4; ++j)
            bfr[j] = *(const short8*)(lds_b + (wn * 64 + j * 16 + lo) * BK + 8 * hi);
        #pragma unroll
        for (int i = 0; i < 4; ++i)
            #pragma unroll
            for (int j = 0; j < 4; ++j)
                acc[i][j] = __builtin_amdgcn_mfma_f32_16x16x32_bf16(af[i], bfr[j], acc[i][j], 0, 0, 0);
        __syncthreads();
    }

    const int m00 = (int)arow0 + wm * 64;
    const int n00 = (int)brow0 + wn * 64;
    if (mode == 1) {
        unsigned short* out = (unsigned short*)outp;
        #pragma unroll
        for (int i = 0; i < 4; ++i)
            #pragma unroll
            for (int j = 0; j < 4; ++j) {
                const int nbase = n00 + j * 16;
                const int qkv = nbase >> 10;          // block-uniform
                #pragma unroll
                for (int e = 0; e < 4; ++e) {
                    const int m = m00 + i * 16 + 4 * hi + e;
                    const int n = nbase + lo;
                    const int b = m >> 11, t = m & 2047;
                    const int h = (n >> 6) & 15, d = n & 63;
                    const int bh = (b << 4) + h;
                    float v = acc[i][j][e];
                    size_t off;
                    if (qkv == 0) {
                        off = ((size_t)bh * T_SEQ + t) * HEAD_DIM + d;
                    } else if (qkv == 1) {
                        v *= 0.125f;  // fold 1/sqrt(Dh) into K
                        off = QKV_STRIDE + ((size_t)bh * T_SEQ + t) * HEAD_DIM + d;
                    } else {
                        off = 2 * QKV_STRIDE + ((size_t)bh * HEAD_DIM + d) * T_SEQ + t;  // V^T
                    }
                    out[off] = f2bf(v);
                }
            }
    } else {
        float* out = (float*)outp;
        #pragma unroll
        for (int i = 0; i < 4; ++i)
            #pragma unroll
            for (int j = 0; j < 4; ++j)
                #pragma unroll
                for (int e = 0; e < 4; ++e) {
                    const int m = m00 + i * 16 + 4 * hi + e;
                    const int n = n00 + j * 16 + lo;
                    out[(size_t)m * N + n] = acc[i][j][e] + bias[n];
                }
    }
}

// ---------------- causal flash attention: 32x32 MFMA, zero-LDS, in-register P ----------------
// 1 wave per (bh, 32-row q-tile). S^T = mfma(K, Q): lane owns q = lane&31,
// k = (reg&3)+8*(reg>>2)+4*(lane>>5). PV as O^T = mfma(V^T-frag, P-frag):
// O^T col = q = lane&31 -> softmax state fully lane-local.
__global__ __launch_bounds__(64) void attn_fwd(
    const unsigned short* __restrict__ QKV,   // Q | K(pre-scaled) | V^T
    unsigned short* __restrict__ ctx)
{
    const int qb = (int)(gridDim.x - 1 - blockIdx.x);  // longest-first
    const int bh = blockIdx.y;
    const int b = bh >> 4, h = bh & 15;
    const int l = threadIdx.x;
    const int l31 = l & 31, hi1 = l >> 5;
    const int q0 = qb * 32;
    const int q = q0 + l31;

    const unsigned short* Qb = QKV + (size_t)bh * T_SEQ * HEAD_DIM;
    const unsigned short* Kb = QKV + QKV_STRIDE + (size_t)bh * T_SEQ * HEAD_DIM;
    const unsigned short* Vb = QKV + 2 * QKV_STRIDE + (size_t)bh * HEAD_DIM * T_SEQ;

    short8 qf[4];
    #pragma unroll
    for (int st = 0; st < 4; ++st)
        qf[st] = *(const short8*)(Qb + (size_t)q * 64 + 16 * st + 8 * hi1);

    f32x16 o0, o1;
    #pragma unroll
    for (int r = 0; r < 16; ++r) { o0[r] = 0.f; o1[r] = 0.f; }
    float mrun = -3e38f, lsum = 0.f;

    for (int kb = 0; kb <= qb; ++kb) {
        const int kbase = kb * 32;
        f32x16 s_;
        #pragma unroll
        for (int r = 0; r < 16; ++r) s_[r] = 0.f;
        #pragma unroll
        for (int st = 0; st < 4; ++st) {
            const short8 kf = *(const short8*)(Kb + (size_t)(kbase + l31) * 64 + 16 * st + 8 * hi1);
            s_ = __builtin_amdgcn_mfma_f32_32x32x16_bf16(kf, qf[st], s_, 0, 0, 0);
        }
        if (kb == qb) {  // diagonal block: mask k > q
            #pragma unroll
            for (int r = 0; r < 16; ++r)
                if ((r & 3) + 8 * (r >> 2) + 4 * hi1 > l31) s_[r] = -3e38f;
        }
        // per-q max: 15 in-lane + 1 cross-half shuffle
        float pm = s_[0];
        #pragma unroll
        for (int r = 1; r < 16; ++r) pm = fmaxf(pm, s_[r]);
        pm = fmaxf(pm, __shfl_xor(pm, 32));
        if (__any(pm > mrun + 8.0f)) {   // defer-max (T13)
            const float mnew = fmaxf(mrun, pm);
            const float sc = __expf(mrun - mnew);
            mrun = mnew;
            lsum *= sc;
            #pragma unroll
            for (int r = 0; r < 16; ++r) { o0[r] *= sc; o1[r] *= sc; }
        }
        float p[16];
        #pragma unroll
        for (int r = 0; r < 16; ++r) p[r] = __expf(s_[r] - mrun);
        float rs = (((p[0] + p[1]) + (p[2] + p[3])) + ((p[4] + p[5]) + (p[6] + p[7])))
                 + (((p[8] + p[9]) + (p[10] + p[11])) + ((p[12] + p[13]) + (p[14] + p[15])));
        rs += __shfl_xor(rs, 32);
        lsum += rs;
        // pack P to bf16 pairs: c_i covers k-octaves {0,8,16,24} x e-pairs
        unsigned c0, c1, c2, c3, c4, c5, c6, c7;
        asm volatile("v_cvt_pk_bf16_f32 %0, %1, %2" : "=v"(c0) : "v"(p[0]),  "v"(p[1]));
        asm volatile("v_cvt_pk_bf16_f32 %0, %1, %2" : "=v"(c1) : "v"(p[2]),  "v"(p[3]));
        asm volatile("v_cvt_pk_bf16_f32 %0, %1, %2" : "=v"(c2) : "v"(p[4]),  "v"(p[5]));
        asm volatile("v_cvt_pk_bf16_f32 %0, %1, %2" : "=v"(c3) : "v"(p[6]),  "v"(p[7]));
        asm volatile("v_cvt_pk_bf16_f32 %0, %1, %2" : "=v"(c4) : "v"(p[8]),  "v"(p[9]));
        asm volatile("v_cvt_pk_bf16_f32 %0, %1, %2" : "=v"(c5) : "v"(p[10]), "v"(p[11]));
        asm volatile("v_cvt_pk_bf16_f32 %0, %1, %2" : "=v"(c6) : "v"(p[12]), "v"(p[13]));
        asm volatile("v_cvt_pk_bf16_f32 %0, %1, %2" : "=v"(c7) : "v"(p[14]), "v"(p[15]));
        // half-exchange lane l <-> l+32: builds B-frag words (k = 8*hi1+0..7 per step)
        asm volatile("v_permlane32_swap_b32 %0, %1" : "+v"(c0), "+v"(c2));  // s=0: w0, w2
        asm volatile("v_permlane32_swap_b32 %0, %1" : "+v"(c1), "+v"(c3));  // s=0: w1, w3
        asm volatile("v_permlane32_swap_b32 %0, %1" : "+v"(c4), "+v"(c6));  // s=1: w0, w2
        asm volatile("v_permlane32_swap_b32 %0, %1" : "+v"(c5), "+v"(c7));  // s=1: w1, w3
        union { short8 v; unsigned u[4]; } pb0, pb1;
        pb0.u[0] = c0; pb0.u[1] = c1; pb0.u[2] = c2; pb0.u[3] = c3;
        pb1.u[0] = c4; pb1.u[1] = c5; pb1.u[2] = c6; pb1.u[3] = c7;
        // PV: O^T[d][q] accumulate; A = V^T fragment (row d, contiguous k), B = P
        const short8 vf00 = *(const short8*)(Vb + (size_t)(l31) * T_SEQ      + kbase      + 8 * hi1);
        const short8 vf01 = *(const short8*)(Vb + (size_t)(l31) * T_SEQ      + kbase + 16 + 8 * hi1);
        const short8 vf10 = *(const short8*)(Vb + (size_t)(32 + l31) * T_SEQ + kbase      + 8 * hi1);
        const short8 vf11 = *(const short8*)(Vb + (size_t)(32 + l31) * T_SEQ + kbase + 16 + 8 * hi1);
        o0 = __builtin_amdgcn_mfma_f32_32x32x16_bf16(vf00, pb0.v, o0, 0, 0, 0);
        o0 = __builtin_amdgcn_mfma_f32_32x32x16_bf16(vf01, pb1.v, o0, 0, 0, 0);
        o1 = __builtin_amdgcn_mfma_f32_32x32x16_bf16(vf10, pb0.v, o1, 0, 0, 0);
        o1 = __builtin_amdgcn_mfma_f32_32x32x16_bf16(vf11, pb1.v, o1, 0, 0, 0);
    }
    // epilogue: O^T: lane q = l31, d = (reg&3)+8*(reg>>2)+4*hi1 (+32 for o1)
    const float inv = 1.0f / lsum;
    unsigned short* crow = ctx + (size_t)(b * T_SEQ + q) * D_MODEL + h * 64;
    #pragma unroll
    for (int rq = 0; rq < 4; ++rq) {
        const int d0 = 8 * rq + 4 * hi1;
        u16x4 ov;
        ov.x = f2bf(o0[4 * rq + 0] * inv);
        ov.y = f2bf(o0[4 * rq + 1] * inv);
        ov.z = f2bf(o0[4 * rq + 2] * inv);
        ov.w = f2bf(o0[4 * rq + 3] * inv);
        *(u16x4*)(crow + d0) = ov;
        u16x4 ov1;
        ov1.x = f2bf(o1[4 * rq + 0] * inv);
        ov1.y = f2bf(o1[4 * rq + 1] * inv);
        ov1.z = f2bf(o1[4 * rq + 2] * inv);
        ov1.w = f2bf(o1[4 * rq + 3] * inv);
        *(u16x4*)(crow + 32 + d0) = ov1;
    }
}

extern "C" void kernel_launch(void* const* d_in, const int* in_sizes, int n_in,
                              void* d_out, int out_size, void* d_ws, size_t ws_size,
                              hipStream_t stream)
{
    const float* x  = (const float*)d_in[0];
    const float* Wq = (const float*)d_in[1];
    const float* Wk = (const float*)d_in[2];
    const float* Wv = (const float*)d_in[3];
    const float* Wo = (const float*)d_in[4];
    const float* bo = (const float*)d_in[5];
    float* out = (float*)d_out;

    char* ws = (char*)d_ws;
    unsigned short* x_bf = (unsigned short*)(ws);                  // 8 MiB [4096][1024]
    unsigned short* WqT  = (unsigned short*)(ws + (8u << 20));     // 2 MiB
    unsigned short* WkT  = (unsigned short*)(ws + (10u << 20));    // 2 MiB
    unsigned short* WvT  = (unsigned short*)(ws + (12u << 20));    // 2 MiB
    unsigned short* WoT  = (unsigned short*)(ws + (14u << 20));    // 2 MiB
    unsigned short* QKV  = (unsigned short*)(ws + (16u << 20));    // 24 MiB: Q | K*0.125 | V^T
    unsigned short* ctx  = (unsigned short*)(ws + (40u << 20));    // 8 MiB [4096][1024]
    (void)in_sizes; (void)n_in; (void)out_size; (void)ws_size;

    cast_x<<<dim3((M_TOK * D_MODEL / 4 + 255) / 256), 256, 0, stream>>>(x, x_bf, M_TOK * D_MODEL / 4);
    transpose_cast4<<<dim3(32, 32, 4), 256, 0, stream>>>(Wq, Wk, Wv, Wo, WqT, WkT, WvT, WoT);

    gemm_bf16<<<dim3(M_TOK / BM, 3072 / BN), 256, 0, stream>>>(
        x_bf, WqT, QKV, nullptr, M_TOK, 3072, D_MODEL, 1);

    attn_fwd<<<dim3(T_SEQ / 32, BATCH * N_HEAD), 64, 0, stream>>>(QKV, ctx);

    gemm_bf16<<<dim3(M_TOK / BM, D_MODEL / BN), 256, 0, stream>>>(
        ctx, WoT, out, bo, M_TOK, D_MODEL, D_MODEL, 2);
}

// Round 7
// 266.188 us; speedup vs baseline: 1.0481x; 1.0481x over previous
//
#include <hip/hip_runtime.h>
#include <hip/hip_bf16.h>

typedef __attribute__((ext_vector_type(8))) short short8;
typedef __attribute__((ext_vector_type(4))) float f32x4;
typedef __attribute__((ext_vector_type(16))) float f32x16;
typedef __attribute__((ext_vector_type(4))) unsigned short u16x4;

#define D_MODEL 1024
#define N_HEAD 16
#define HEAD_DIM 64
#define T_SEQ 2048
#define BATCH 2
#define M_TOK (BATCH * T_SEQ) /* 4096 */
#define QKV_STRIDE ((size_t)M_TOK * D_MODEL) /* elems per Q/K/V buffer */

__device__ __forceinline__ unsigned short f2bf(float f) {
    union { float f; unsigned u; } v; v.f = f;
    unsigned r = (v.u + 0x7fffu + ((v.u >> 16) & 1u)) >> 16;  // RNE
    return (unsigned short)r;
}

__device__ __forceinline__ void load16_lds(const unsigned short* g, unsigned short* l) {
    __builtin_amdgcn_global_load_lds(
        (const __attribute__((address_space(1))) unsigned int*)(g),
        (__attribute__((address_space(3))) unsigned int*)(l),
        16, 0, 0);
}

// ---------------- cast x (f32 -> bf16), vectorized ----------------
__global__ __launch_bounds__(256) void cast_x(const float* __restrict__ in,
                                              unsigned short* __restrict__ out, int n4) {
    int i = blockIdx.x * 256 + threadIdx.x;
    if (i < n4) {
        float4 v = ((const float4*)in)[i];
        u16x4 o;
        o.x = f2bf(v.x); o.y = f2bf(v.y); o.z = f2bf(v.z); o.w = f2bf(v.w);
        ((u16x4*)out)[i] = o;
    }
}

// ---------------- transpose + cast all 4 weights [1024][1024] f32 -> bf16 T ----------------
__global__ __launch_bounds__(256) void transpose_cast4(
    const float* __restrict__ w0, const float* __restrict__ w1,
    const float* __restrict__ w2, const float* __restrict__ w3,
    unsigned short* __restrict__ o0, unsigned short* __restrict__ o1,
    unsigned short* __restrict__ o2, unsigned short* __restrict__ o3)
{
    __shared__ float tile[32][33];
    const float* in; unsigned short* outT;
    switch (blockIdx.z) {
        case 0: in = w0; outT = o0; break;
        case 1: in = w1; outT = o1; break;
        case 2: in = w2; outT = o2; break;
        default: in = w3; outT = o3; break;
    }
    const int R = 1024, C = 1024;
    const int r0 = blockIdx.x * 32, c0 = blockIdx.y * 32;
    const int tx = threadIdx.x & 31, ty = threadIdx.x >> 5;  // ty 0..7
    #pragma unroll
    for (int jj = 0; jj < 32; jj += 8)
        tile[ty + jj][tx] = in[(size_t)(r0 + ty + jj) * C + c0 + tx];
    __syncthreads();
    #pragma unroll
    for (int jj = 0; jj < 32; jj += 8)
        outT[(size_t)(c0 + ty + jj) * R + r0 + tx] = f2bf(tile[tx][ty + jj]);
}

// ---------------- 2-phase pipelined GEMM: C[M,N] = A[M,K] * Bt[N,K]^T ----------------
// 128x128 tile, BK=32, 4 waves, double-buffered LDS, stage(next) overlaps MFMA(cur).
// mode 1: scatter into QKV: Q raw; K scaled by 0.125*log2(e); V transposed [B,H,Dh,T]
// mode 2: f32 out[M,N] + bias[n]
#define BM 128
#define BN 128
#define BK 32
__global__ __launch_bounds__(256) void gemm_bf16(
    const unsigned short* __restrict__ A,
    const unsigned short* __restrict__ Bt,
    void* __restrict__ outp,
    const float* __restrict__ bias,
    int M, int N, int K, int mode)
{
    __shared__ unsigned short lds_a[2][BM * BK];  // 2 x 8 KiB
    __shared__ unsigned short lds_b[2][BN * BK];  // 2 x 8 KiB
    const int tid = threadIdx.x;
    const int w = tid >> 6, l = tid & 63, lo = l & 15, hi = l >> 4;
    const int wm = w >> 1, wn = w & 1;
    const size_t arow0 = (size_t)blockIdx.x * BM;
    const size_t brow0 = (size_t)blockIdx.y * BN;

    f32x4 acc[4][4];
    #pragma unroll
    for (int i = 0; i < 4; ++i)
        #pragma unroll
        for (int j = 0; j < 4; ++j)
            acc[i][j] = (f32x4){0.f, 0.f, 0.f, 0.f};

    const int ch0 = tid, ch1 = 256 + tid;
    const int r0c = ch0 >> 2, c0c = (ch0 & 3) * 8;
    const int r1c = ch1 >> 2, c1c = (ch1 & 3) * 8;
    const unsigned short* Ab0 = A + (arow0 + r0c) * K + c0c;
    const unsigned short* Ab1 = A + (arow0 + r1c) * K + c1c;
    const unsigned short* Bb0 = Bt + (brow0 + r0c) * K + c0c;
    const unsigned short* Bb1 = Bt + (brow0 + r1c) * K + c1c;
    const int woff0 = (0 * 256 + w * 64) * 8, woff1 = (1 * 256 + w * 64) * 8;

#define STAGE(BUF, KOFF)                                   \
    do {                                                   \
        load16_lds(Ab0 + (KOFF), lds_a[BUF] + woff0);      \
        load16_lds(Ab1 + (KOFF), lds_a[BUF] + woff1);      \
        load16_lds(Bb0 + (KOFF), lds_b[BUF] + woff0);      \
        load16_lds(Bb1 + (KOFF), lds_b[BUF] + woff1);      \
    } while (0)

    STAGE(0, 0);
    int cur = 0;
    for (int k0 = 0; k0 < K; k0 += BK) {
        __syncthreads();                       // drains in-flight stage (vmcnt0) + barrier
        if (k0 + BK < K) STAGE(cur ^ 1, k0 + BK);   // overlap next stage with current MFMAs
        short8 af[4], bfr[4];
        #pragma unroll
        for (int i = 0; i < 4; ++i)
            af[i] = *(const short8*)(lds_a[cur] + (wm * 64 + i * 16 + lo) * BK + 8 * hi);
        #pragma unroll
        for (int j = 0; j < 4; ++j)
            bfr[j] = *(const short8*)(lds_b[cur] + (wn * 64 + j * 16 + lo) * BK + 8 * hi);
        #pragma unroll
        for (int i = 0; i < 4; ++i)
            #pragma unroll
            for (int j = 0; j < 4; ++j)
                acc[i][j] = __builtin_amdgcn_mfma_f32_16x16x32_bf16(af[i], bfr[j], acc[i][j], 0, 0, 0);
        cur ^= 1;
    }
#undef STAGE

    const int m00 = (int)arow0 + wm * 64;
    const int n00 = (int)brow0 + wn * 64;
    if (mode == 1) {
        unsigned short* out = (unsigned short*)outp;
        #pragma unroll
        for (int i = 0; i < 4; ++i)
            #pragma unroll
            for (int j = 0; j < 4; ++j) {
                const int nbase = n00 + j * 16;
                const int qkv = nbase >> 10;          // block-uniform
                #pragma unroll
                for (int e = 0; e < 4; ++e) {
                    const int m = m00 + i * 16 + 4 * hi + e;
                    const int n = nbase + lo;
                    const int b = m >> 11, t = m & 2047;
                    const int h = (n >> 6) & 15, d = n & 63;
                    const int bh = (b << 4) + h;
                    float v = acc[i][j][e];
                    size_t off;
                    if (qkv == 0) {
                        off = ((size_t)bh * T_SEQ + t) * HEAD_DIM + d;
                    } else if (qkv == 1) {
                        v *= 0.18033688f;  // 1/sqrt(Dh) * log2(e): exp -> exp2 in attn
                        off = QKV_STRIDE + ((size_t)bh * T_SEQ + t) * HEAD_DIM + d;
                    } else {
                        off = 2 * QKV_STRIDE + ((size_t)bh * HEAD_DIM + d) * T_SEQ + t;  // V^T
                    }
                    out[off] = f2bf(v);
                }
            }
    } else {
        float* out = (float*)outp;
        #pragma unroll
        for (int i = 0; i < 4; ++i)
            #pragma unroll
            for (int j = 0; j < 4; ++j)
                #pragma unroll
                for (int e = 0; e < 4; ++e) {
                    const int m = m00 + i * 16 + 4 * hi + e;
                    const int n = n00 + j * 16 + lo;
                    out[(size_t)m * N + n] = acc[i][j][e] + bias[n];
                }
    }
}

// ---------------- causal flash attention: 32x32 MFMA, zero-LDS, 2-deep K/V prefetch ----------
// 1 wave per (bh, 32-row q-tile). S^T = mfma(K, Q): lane owns q = lane&31,
// k = (reg&3)+8*(reg>>2)+4*(lane>>5). PV as O^T = mfma(V^T-frag, P-frag).
// Softmax in base-2 (log2(e) folded into K). Register double-buffer breaks the
// per-iteration memory-latency chain (R5: 4.7k cyc/iter serial).
__global__ __launch_bounds__(64) void attn_fwd(
    const unsigned short* __restrict__ QKV,   // Q | K(pre-scaled) | V^T
    unsigned short* __restrict__ ctx)
{
    const int qb = (int)(gridDim.x - 1 - blockIdx.x);  // longest-first
    const int bh = blockIdx.y;
    const int b = bh >> 4, h = bh & 15;
    const int l = threadIdx.x;
    const int l31 = l & 31, hi1 = l >> 5;
    const int q0 = qb * 32;
    const int q = q0 + l31;

    const unsigned short* Qb = QKV + (size_t)bh * T_SEQ * HEAD_DIM;
    const unsigned short* Kb = QKV + QKV_STRIDE + (size_t)bh * T_SEQ * HEAD_DIM;
    const unsigned short* Vb = QKV + 2 * QKV_STRIDE + (size_t)bh * HEAD_DIM * T_SEQ;

    short8 qf[4];
    #pragma unroll
    for (int st = 0; st < 4; ++st)
        qf[st] = *(const short8*)(Qb + (size_t)q * 64 + 16 * st + 8 * hi1);

    f32x16 o0, o1;
    #pragma unroll
    for (int r = 0; r < 16; ++r) { o0[r] = 0.f; o1[r] = 0.f; }
    float mrun = -3e38f, lsum = 0.f;

    short8 kA0, kA1, kA2, kA3, vA0, vA1, vA2, vA3;
    short8 kB0, kB1, kB2, kB3, vB0, vB1, vB2, vB3;

#define PREFETCH(KB1, K0, K1, K2, K3, V0, V1, V2, V3)                              \
    if ((KB1) <= qb) {                                                             \
        const unsigned short* kp = Kb + (size_t)((KB1) * 32 + l31) * 64 + 8 * hi1; \
        K0 = *(const short8*)(kp);      K1 = *(const short8*)(kp + 16);            \
        K2 = *(const short8*)(kp + 32); K3 = *(const short8*)(kp + 48);            \
        const unsigned short* vp = Vb + (size_t)l31 * T_SEQ + (KB1) * 32 + 8 * hi1;\
        V0 = *(const short8*)(vp);                  V1 = *(const short8*)(vp + 16);\
        V2 = *(const short8*)(vp + 32 * T_SEQ);     V3 = *(const short8*)(vp + 32 * T_SEQ + 16); \
    }

#define BODY(KB_, K0, K1, K2, K3, V0, V1, V2, V3)                                  \
    {                                                                              \
        f32x16 s_;                                                                 \
        _Pragma("unroll")                                                          \
        for (int r = 0; r < 16; ++r) s_[r] = 0.f;                                  \
        s_ = __builtin_amdgcn_mfma_f32_32x32x16_bf16(K0, qf[0], s_, 0, 0, 0);      \
        s_ = __builtin_amdgcn_mfma_f32_32x32x16_bf16(K1, qf[1], s_, 0, 0, 0);      \
        s_ = __builtin_amdgcn_mfma_f32_32x32x16_bf16(K2, qf[2], s_, 0, 0, 0);      \
        s_ = __builtin_amdgcn_mfma_f32_32x32x16_bf16(K3, qf[3], s_, 0, 0, 0);      \
        if ((KB_) == qb) {                                                         \
            _Pragma("unroll")                                                      \
            for (int r = 0; r < 16; ++r)                                           \
                if ((r & 3) + 8 * (r >> 2) + 4 * hi1 > l31) s_[r] = -3e38f;        \
        }                                                                          \
        float pm = s_[0];                                                          \
        _Pragma("unroll")                                                          \
        for (int r = 1; r < 16; ++r) pm = fmaxf(pm, s_[r]);                        \
        pm = fmaxf(pm, __shfl_xor(pm, 32));                                        \
        if (__any(pm > mrun + 8.0f)) {                                             \
            const float mnew = fmaxf(mrun, pm);                                    \
            const float sc = exp2f(mrun - mnew);                                   \
            mrun = mnew;                                                           \
            lsum *= sc;                                                            \
            _Pragma("unroll")                                                      \
            for (int r = 0; r < 16; ++r) { o0[r] *= sc; o1[r] *= sc; }             \
        }                                                                          \
        float p[16];                                                               \
        _Pragma("unroll")                                                          \
        for (int r = 0; r < 16; ++r) p[r] = exp2f(s_[r] - mrun);                   \
        float rs = (((p[0] + p[1]) + (p[2] + p[3])) + ((p[4] + p[5]) + (p[6] + p[7])))   \
                 + (((p[8] + p[9]) + (p[10] + p[11])) + ((p[12] + p[13]) + (p[14] + p[15]))); \
        rs += __shfl_xor(rs, 32);                                                  \
        lsum += rs;                                                                \
        unsigned c0, c1, c2, c3, c4, c5, c6, c7;                                   \
        asm volatile("v_cvt_pk_bf16_f32 %0, %1, %2" : "=v"(c0) : "v"(p[0]),  "v"(p[1]));  \
        asm volatile("v_cvt_pk_bf16_f32 %0, %1, %2" : "=v"(c1) : "v"(p[2]),  "v"(p[3]));  \
        asm volatile("v_cvt_pk_bf16_f32 %0, %1, %2" : "=v"(c2) : "v"(p[4]),  "v"(p[5]));  \
        asm volatile("v_cvt_pk_bf16_f32 %0, %1, %2" : "=v"(c3) : "v"(p[6]),  "v"(p[7]));  \
        asm volatile("v_cvt_pk_bf16_f32 %0, %1, %2" : "=v"(c4) : "v"(p[8]),  "v"(p[9]));  \
        asm volatile("v_cvt_pk_bf16_f32 %0, %1, %2" : "=v"(c5) : "v"(p[10]), "v"(p[11])); \
        asm volatile("v_cvt_pk_bf16_f32 %0, %1, %2" : "=v"(c6) : "v"(p[12]), "v"(p[13])); \
        asm volatile("v_cvt_pk_bf16_f32 %0, %1, %2" : "=v"(c7) : "v"(p[14]), "v"(p[15])); \
        asm volatile("v_permlane32_swap_b32 %0, %1" : "+v"(c0), "+v"(c2));         \
        asm volatile("v_permlane32_swap_b32 %0, %1" : "+v"(c1), "+v"(c3));         \
        asm volatile("v_permlane32_swap_b32 %0, %1" : "+v"(c4), "+v"(c6));         \
        asm volatile("v_permlane32_swap_b32 %0, %1" : "+v"(c5), "+v"(c7));         \
        union { short8 v; unsigned u[4]; } pb0, pb1;                               \
        pb0.u[0] = c0; pb0.u[1] = c1; pb0.u[2] = c2; pb0.u[3] = c3;                \
        pb1.u[0] = c4; pb1.u[1] = c5; pb1.u[2] = c6; pb1.u[3] = c7;                \
        o0 = __builtin_amdgcn_mfma_f32_32x32x16_bf16(V0, pb0.v, o0, 0, 0, 0);      \
        o0 = __builtin_amdgcn_mfma_f32_32x32x16_bf16(V1, pb1.v, o0, 0, 0, 0);      \
        o1 = __builtin_amdgcn_mfma_f32_32x32x16_bf16(V2, pb0.v, o1, 0, 0, 0);      \
        o1 = __builtin_amdgcn_mfma_f32_32x32x16_bf16(V3, pb1.v, o1, 0, 0, 0);      \
    }

    PREFETCH(0, kA0, kA1, kA2, kA3, vA0, vA1, vA2, vA3)
    for (int kb = 0; kb <= qb; kb += 2) {
        PREFETCH(kb + 1, kB0, kB1, kB2, kB3, vB0, vB1, vB2, vB3)
        BODY(kb, kA0, kA1, kA2, kA3, vA0, vA1, vA2, vA3)
        if (kb + 1 <= qb) {
            PREFETCH(kb + 2, kA0, kA1, kA2, kA3, vA0, vA1, vA2, vA3)
            BODY(kb + 1, kB0, kB1, kB2, kB3, vB0, vB1, vB2, vB3)
        }
    }
#undef PREFETCH
#undef BODY

    // epilogue: O^T: lane q = l31, d = (reg&3)+8*(reg>>2)+4*hi1 (+32 for o1)
    const float inv = 1.0f / lsum;
    unsigned short* crow = ctx + (size_t)(b * T_SEQ + q) * D_MODEL + h * 64;
    #pragma unroll
    for (int rq = 0; rq < 4; ++rq) {
        const int d0 = 8 * rq + 4 * hi1;
        u16x4 ov;
        ov.x = f2bf(o0[4 * rq + 0] * inv);
        ov.y = f2bf(o0[4 * rq + 1] * inv);
        ov.z = f2bf(o0[4 * rq + 2] * inv);
        ov.w = f2bf(o0[4 * rq + 3] * inv);
        *(u16x4*)(crow + d0) = ov;
        u16x4 ov1;
        ov1.x = f2bf(o1[4 * rq + 0] * inv);
        ov1.y = f2bf(o1[4 * rq + 1] * inv);
        ov1.z = f2bf(o1[4 * rq + 2] * inv);
        ov1.w = f2bf(o1[4 * rq + 3] * inv);
        *(u16x4*)(crow + 32 + d0) = ov1;
    }
}

extern "C" void kernel_launch(void* const* d_in, const int* in_sizes, int n_in,
                              void* d_out, int out_size, void* d_ws, size_t ws_size,
                              hipStream_t stream)
{
    const float* x  = (const float*)d_in[0];
    const float* Wq = (const float*)d_in[1];
    const float* Wk = (const float*)d_in[2];
    const float* Wv = (const float*)d_in[3];
    const float* Wo = (const float*)d_in[4];
    const float* bo = (const float*)d_in[5];
    float* out = (float*)d_out;

    char* ws = (char*)d_ws;
    unsigned short* x_bf = (unsigned short*)(ws);                  // 8 MiB [4096][1024]
    unsigned short* WqT  = (unsigned short*)(ws + (8u << 20));     // 2 MiB
    unsigned short* WkT  = (unsigned short*)(ws + (10u << 20));    // 2 MiB
    unsigned short* WvT  = (unsigned short*)(ws + (12u << 20));    // 2 MiB
    unsigned short* WoT  = (unsigned short*)(ws + (14u << 20));    // 2 MiB
    unsigned short* QKV  = (unsigned short*)(ws + (16u << 20));    // 24 MiB: Q | K*scale | V^T
    unsigned short* ctx  = (unsigned short*)(ws + (40u << 20));    // 8 MiB [4096][1024]
    (void)in_sizes; (void)n_in; (void)out_size; (void)ws_size;

    cast_x<<<dim3((M_TOK * D_MODEL / 4 + 255) / 256), 256, 0, stream>>>(x, x_bf, M_TOK * D_MODEL / 4);
    transpose_cast4<<<dim3(32, 32, 4), 256, 0, stream>>>(Wq, Wk, Wv, Wo, WqT, WkT, WvT, WoT);

    gemm_bf16<<<dim3(M_TOK / BM, 3072 / BN), 256, 0, stream>>>(
        x_bf, WqT, QKV, nullptr, M_TOK, 3072, D_MODEL, 1);

    attn_fwd<<<dim3(T_SEQ / 32, BATCH * N_HEAD), 64, 0, stream>>>(QKV, ctx);

    gemm_bf16<<<dim3(M_TOK / BM, D_MODEL / BN), 256, 0, stream>>>(
        ctx, WoT, out, bo, M_TOK, D_MODEL, D_MODEL, 2);
}

// Round 8
// 249.085 us; speedup vs baseline: 1.1201x; 1.0687x over previous
//
#include <hip/hip_runtime.h>
#include <hip/hip_bf16.h>

typedef __attribute__((ext_vector_type(8))) short short8;
typedef __attribute__((ext_vector_type(4))) float f32x4;
typedef __attribute__((ext_vector_type(16))) float f32x16;
typedef __attribute__((ext_vector_type(4))) unsigned short u16x4;

#define D_MODEL 1024
#define N_HEAD 16
#define HEAD_DIM 64
#define T_SEQ 2048
#define BATCH 2
#define M_TOK (BATCH * T_SEQ) /* 4096 */
#define QKV_STRIDE ((size_t)M_TOK * D_MODEL) /* elems per Q/K/V buffer */

__device__ __forceinline__ unsigned short f2bf(float f) {
    union { float f; unsigned u; } v; v.f = f;
    unsigned r = (v.u + 0x7fffu + ((v.u >> 16) & 1u)) >> 16;  // RNE
    return (unsigned short)r;
}

__device__ __forceinline__ float exp2_fast(float x) {
    float r;
    asm("v_exp_f32 %0, %1" : "=v"(r) : "v"(x));   // 2^x, ~1ulp: fine for softmax
    return r;
}

__device__ __forceinline__ void load16_lds(const unsigned short* g, unsigned short* l) {
    __builtin_amdgcn_global_load_lds(
        (const __attribute__((address_space(1))) unsigned int*)(g),
        (__attribute__((address_space(3))) unsigned int*)(l),
        16, 0, 0);
}

// ---------------- cast x (f32 -> bf16), vectorized ----------------
__global__ __launch_bounds__(256) void cast_x(const float* __restrict__ in,
                                              unsigned short* __restrict__ out, int n4) {
    int i = blockIdx.x * 256 + threadIdx.x;
    if (i < n4) {
        float4 v = ((const float4*)in)[i];
        u16x4 o;
        o.x = f2bf(v.x); o.y = f2bf(v.y); o.z = f2bf(v.z); o.w = f2bf(v.w);
        ((u16x4*)out)[i] = o;
    }
}

// ---------------- transpose + cast all 4 weights [1024][1024] f32 -> bf16 T ----------------
__global__ __launch_bounds__(256) void transpose_cast4(
    const float* __restrict__ w0, const float* __restrict__ w1,
    const float* __restrict__ w2, const float* __restrict__ w3,
    unsigned short* __restrict__ o0, unsigned short* __restrict__ o1,
    unsigned short* __restrict__ o2, unsigned short* __restrict__ o3)
{
    __shared__ float tile[32][33];
    const float* in; unsigned short* outT;
    switch (blockIdx.z) {
        case 0: in = w0; outT = o0; break;
        case 1: in = w1; outT = o1; break;
        case 2: in = w2; outT = o2; break;
        default: in = w3; outT = o3; break;
    }
    const int R = 1024, C = 1024;
    const int r0 = blockIdx.x * 32, c0 = blockIdx.y * 32;
    const int tx = threadIdx.x & 31, ty = threadIdx.x >> 5;  // ty 0..7
    #pragma unroll
    for (int jj = 0; jj < 32; jj += 8)
        tile[ty + jj][tx] = in[(size_t)(r0 + ty + jj) * C + c0 + tx];
    __syncthreads();
    #pragma unroll
    for (int jj = 0; jj < 32; jj += 8)
        outT[(size_t)(c0 + ty + jj) * R + r0 + tx] = f2bf(tile[tx][ty + jj]);
}

// ---------------- 2-phase pipelined GEMM: C[M,N] = A[M,K] * Bt[N,K]^T ----------------
// 128x128 tile, BK=32, 4 waves, double-buffered LDS, stage(next) overlaps MFMA(cur).
// mode 1: scatter into QKV: Q raw; K scaled by 0.125*log2(e); V transposed [B,H,Dh,T]
// mode 2: f32 out[M,N] + bias[n]
#define BM 128
#define BN 128
#define BK 32
__global__ __launch_bounds__(256) void gemm_bf16(
    const unsigned short* __restrict__ A,
    const unsigned short* __restrict__ Bt,
    void* __restrict__ outp,
    const float* __restrict__ bias,
    int M, int N, int K, int mode)
{
    __shared__ unsigned short lds_a[2][BM * BK];  // 2 x 8 KiB
    __shared__ unsigned short lds_b[2][BN * BK];  // 2 x 8 KiB
    const int tid = threadIdx.x;
    const int w = tid >> 6, l = tid & 63, lo = l & 15, hi = l >> 4;
    const int wm = w >> 1, wn = w & 1;
    const size_t arow0 = (size_t)blockIdx.x * BM;
    const size_t brow0 = (size_t)blockIdx.y * BN;

    f32x4 acc[4][4];
    #pragma unroll
    for (int i = 0; i < 4; ++i)
        #pragma unroll
        for (int j = 0; j < 4; ++j)
            acc[i][j] = (f32x4){0.f, 0.f, 0.f, 0.f};

    const int ch0 = tid, ch1 = 256 + tid;
    const int r0c = ch0 >> 2, c0c = (ch0 & 3) * 8;
    const int r1c = ch1 >> 2, c1c = (ch1 & 3) * 8;
    const unsigned short* Ab0 = A + (arow0 + r0c) * K + c0c;
    const unsigned short* Ab1 = A + (arow0 + r1c) * K + c1c;
    const unsigned short* Bb0 = Bt + (brow0 + r0c) * K + c0c;
    const unsigned short* Bb1 = Bt + (brow0 + r1c) * K + c1c;
    const int woff0 = (0 * 256 + w * 64) * 8, woff1 = (1 * 256 + w * 64) * 8;

#define STAGE(BUF, KOFF)                                   \
    do {                                                   \
        load16_lds(Ab0 + (KOFF), lds_a[BUF] + woff0);      \
        load16_lds(Ab1 + (KOFF), lds_a[BUF] + woff1);      \
        load16_lds(Bb0 + (KOFF), lds_b[BUF] + woff0);      \
        load16_lds(Bb1 + (KOFF), lds_b[BUF] + woff1);      \
    } while (0)

    STAGE(0, 0);
    int cur = 0;
    for (int k0 = 0; k0 < K; k0 += BK) {
        __syncthreads();                       // drains in-flight stage (vmcnt0) + barrier
        if (k0 + BK < K) STAGE(cur ^ 1, k0 + BK);   // overlap next stage with current MFMAs
        short8 af[4], bfr[4];
        #pragma unroll
        for (int i = 0; i < 4; ++i)
            af[i] = *(const short8*)(lds_a[cur] + (wm * 64 + i * 16 + lo) * BK + 8 * hi);
        #pragma unroll
        for (int j = 0; j < 4; ++j)
            bfr[j] = *(const short8*)(lds_b[cur] + (wn * 64 + j * 16 + lo) * BK + 8 * hi);
        #pragma unroll
        for (int i = 0; i < 4; ++i)
            #pragma unroll
            for (int j = 0; j < 4; ++j)
                acc[i][j] = __builtin_amdgcn_mfma_f32_16x16x32_bf16(af[i], bfr[j], acc[i][j], 0, 0, 0);
        cur ^= 1;
    }
#undef STAGE

    const int m00 = (int)arow0 + wm * 64;
    const int n00 = (int)brow0 + wn * 64;
    if (mode == 1) {
        unsigned short* out = (unsigned short*)outp;
        #pragma unroll
        for (int i = 0; i < 4; ++i)
            #pragma unroll
            for (int j = 0; j < 4; ++j) {
                const int nbase = n00 + j * 16;
                const int qkv = nbase >> 10;          // block-uniform
                #pragma unroll
                for (int e = 0; e < 4; ++e) {
                    const int m = m00 + i * 16 + 4 * hi + e;
                    const int n = nbase + lo;
                    const int b = m >> 11, t = m & 2047;
                    const int h = (n >> 6) & 15, d = n & 63;
                    const int bh = (b << 4) + h;
                    float v = acc[i][j][e];
                    size_t off;
                    if (qkv == 0) {
                        off = ((size_t)bh * T_SEQ + t) * HEAD_DIM + d;
                    } else if (qkv == 1) {
                        v *= 0.18033688f;  // 1/sqrt(Dh) * log2(e): exp -> exp2 in attn
                        off = QKV_STRIDE + ((size_t)bh * T_SEQ + t) * HEAD_DIM + d;
                    } else {
                        off = 2 * QKV_STRIDE + ((size_t)bh * HEAD_DIM + d) * T_SEQ + t;  // V^T
                    }
                    out[off] = f2bf(v);
                }
            }
    } else {
        float* out = (float*)outp;
        #pragma unroll
        for (int i = 0; i < 4; ++i)
            #pragma unroll
            for (int j = 0; j < 4; ++j)
                #pragma unroll
                for (int e = 0; e < 4; ++e) {
                    const int m = m00 + i * 16 + 4 * hi + e;
                    const int n = n00 + j * 16 + lo;
                    out[(size_t)m * N + n] = acc[i][j][e] + bias[n];
                }
    }
}

// ---------------- causal flash attention: 32x32 MFMA, split-K x4 waves ----------------
// Block = 256 threads = 4 waves, all on ONE (bh, 32-row q-tile). Wave w handles
// k-blocks kb ≡ w (mod 4) with private (m,l,O^T); LDS merge at the end.
// S^T = mfma(K, Q): lane owns q = lane&31, k = (reg&3)+8*(reg>>2)+4*(lane>>5).
// PV as O^T = mfma(V^T-frag, P-frag): O^T col = q -> softmax state lane-local.
__global__ __launch_bounds__(256) void attn_fwd(
    const unsigned short* __restrict__ QKV,   // Q | K(pre-scaled by 0.125*log2e) | V^T
    unsigned short* __restrict__ ctx)
{
    const int qb = (int)(gridDim.x - 1 - blockIdx.x);  // longest-first
    const int bh = blockIdx.y;
    const int b = bh >> 4, h = bh & 15;
    const int tid = threadIdx.x;
    const int wid = tid >> 6;
    const int l = tid & 63;
    const int l31 = l & 31, hi1 = l >> 5;
    const int q0 = qb * 32;
    const int q = q0 + l31;

    const unsigned short* Qb = QKV + (size_t)bh * T_SEQ * HEAD_DIM;
    const unsigned short* Kb = QKV + QKV_STRIDE + (size_t)bh * T_SEQ * HEAD_DIM;
    const unsigned short* Vb = QKV + 2 * QKV_STRIDE + (size_t)bh * HEAD_DIM * T_SEQ;

    __shared__ float cm[4][32], cl[4][32];
    __shared__ float co[4][64][20];   // 16 f32 payload + 4 pad -> 80B rows (16B aligned)

    short8 qf[4];
    #pragma unroll
    for (int st = 0; st < 4; ++st)
        qf[st] = *(const short8*)(Qb + (size_t)q * 64 + 16 * st + 8 * hi1);

    f32x16 o0, o1;
    #pragma unroll
    for (int r = 0; r < 16; ++r) { o0[r] = 0.f; o1[r] = 0.f; }
    float mrun = -3e38f, lsum = 0.f;

    // wave-private walk: kb = wid, wid+4, ...
    const unsigned short* kp = Kb + ((size_t)(wid * 32 + l31)) * 64 + 8 * hi1;
    const unsigned short* vp = Vb + (size_t)l31 * T_SEQ + wid * 32 + 8 * hi1;
    for (int kb = wid; kb <= qb; kb += 4) {
        const short8 k0 = *(const short8*)(kp);
        const short8 k1 = *(const short8*)(kp + 16);
        const short8 k2 = *(const short8*)(kp + 32);
        const short8 k3 = *(const short8*)(kp + 48);
        const short8 v0 = *(const short8*)(vp);
        const short8 v1 = *(const short8*)(vp + 16);
        const short8 v2 = *(const short8*)(vp + 32 * T_SEQ);
        const short8 v3 = *(const short8*)(vp + 32 * T_SEQ + 16);
        kp += 4 * 32 * 64;   // +4 k-blocks of rows
        vp += 4 * 32;        // +4 k-blocks of cols

        f32x16 s_;
        #pragma unroll
        for (int r = 0; r < 16; ++r) s_[r] = 0.f;
        s_ = __builtin_amdgcn_mfma_f32_32x32x16_bf16(k0, qf[0], s_, 0, 0, 0);
        s_ = __builtin_amdgcn_mfma_f32_32x32x16_bf16(k1, qf[1], s_, 0, 0, 0);
        s_ = __builtin_amdgcn_mfma_f32_32x32x16_bf16(k2, qf[2], s_, 0, 0, 0);
        s_ = __builtin_amdgcn_mfma_f32_32x32x16_bf16(k3, qf[3], s_, 0, 0, 0);
        if (kb == qb) {   // diagonal block: mask k > q
            #pragma unroll
            for (int r = 0; r < 16; ++r)
                if ((r & 3) + 8 * (r >> 2) + 4 * hi1 > l31) s_[r] = -3e38f;
        }
        float pm = s_[0];
        #pragma unroll
        for (int r = 1; r < 16; ++r) pm = fmaxf(pm, s_[r]);
        pm = fmaxf(pm, __shfl_xor(pm, 32));
        if (__any(pm > mrun + 8.0f)) {       // defer-max (T13)
            const float mnew = fmaxf(mrun, pm);
            const float sc = exp2_fast(mrun - mnew);
            mrun = mnew;
            lsum *= sc;
            #pragma unroll
            for (int r = 0; r < 16; ++r) { o0[r] *= sc; o1[r] *= sc; }
        }
        float p[16];
        #pragma unroll
        for (int r = 0; r < 16; ++r) p[r] = exp2_fast(s_[r] - mrun);
        float rs = (((p[0] + p[1]) + (p[2] + p[3])) + ((p[4] + p[5]) + (p[6] + p[7])))
                 + (((p[8] + p[9]) + (p[10] + p[11])) + ((p[12] + p[13]) + (p[14] + p[15])));
        rs += __shfl_xor(rs, 32);
        lsum += rs;
        unsigned c0, c1, c2, c3, c4, c5, c6, c7;
        asm volatile("v_cvt_pk_bf16_f32 %0, %1, %2" : "=v"(c0) : "v"(p[0]),  "v"(p[1]));
        asm volatile("v_cvt_pk_bf16_f32 %0, %1, %2" : "=v"(c1) : "v"(p[2]),  "v"(p[3]));
        asm volatile("v_cvt_pk_bf16_f32 %0, %1, %2" : "=v"(c2) : "v"(p[4]),  "v"(p[5]));
        asm volatile("v_cvt_pk_bf16_f32 %0, %1, %2" : "=v"(c3) : "v"(p[6]),  "v"(p[7]));
        asm volatile("v_cvt_pk_bf16_f32 %0, %1, %2" : "=v"(c4) : "v"(p[8]),  "v"(p[9]));
        asm volatile("v_cvt_pk_bf16_f32 %0, %1, %2" : "=v"(c5) : "v"(p[10]), "v"(p[11]));
        asm volatile("v_cvt_pk_bf16_f32 %0, %1, %2" : "=v"(c6) : "v"(p[12]), "v"(p[13]));
        asm volatile("v_cvt_pk_bf16_f32 %0, %1, %2" : "=v"(c7) : "v"(p[14]), "v"(p[15]));
        asm volatile("v_permlane32_swap_b32 %0, %1" : "+v"(c0), "+v"(c2));
        asm volatile("v_permlane32_swap_b32 %0, %1" : "+v"(c1), "+v"(c3));
        asm volatile("v_permlane32_swap_b32 %0, %1" : "+v"(c4), "+v"(c6));
        asm volatile("v_permlane32_swap_b32 %0, %1" : "+v"(c5), "+v"(c7));
        union { short8 v; unsigned u[4]; } pb0, pb1;
        pb0.u[0] = c0; pb0.u[1] = c1; pb0.u[2] = c2; pb0.u[3] = c3;
        pb1.u[0] = c4; pb1.u[1] = c5; pb1.u[2] = c6; pb1.u[3] = c7;
        o0 = __builtin_amdgcn_mfma_f32_32x32x16_bf16(v0, pb0.v, o0, 0, 0, 0);
        o0 = __builtin_amdgcn_mfma_f32_32x32x16_bf16(v1, pb1.v, o0, 0, 0, 0);
        o1 = __builtin_amdgcn_mfma_f32_32x32x16_bf16(v2, pb0.v, o1, 0, 0, 0);
        o1 = __builtin_amdgcn_mfma_f32_32x32x16_bf16(v3, pb1.v, o1, 0, 0, 0);
    }

    // ---- merge 4 wave-partials ----
    if (hi1 == 0) { cm[wid][l31] = mrun; cl[wid][l31] = lsum; }
    __syncthreads();
    const float m0_ = cm[0][l31], m1_ = cm[1][l31], m2_ = cm[2][l31], m3_ = cm[3][l31];
    const float m_g = fmaxf(fmaxf(m0_, m1_), fmaxf(m2_, m3_));
    const float l_g = cl[0][l31] * exp2_fast(m0_ - m_g) + cl[1][l31] * exp2_fast(m1_ - m_g)
                    + cl[2][l31] * exp2_fast(m2_ - m_g) + cl[3][l31] * exp2_fast(m3_ - m_g);
    const float sw = exp2_fast(mrun - m_g);
    const float inv = 1.0f / l_g;
    unsigned short* crow = ctx + (size_t)(b * T_SEQ + q) * D_MODEL + h * 64;

    // phase A: o0 (d = 0..31)
    #pragma unroll
    for (int c = 0; c < 4; ++c) {
        f32x4 t = {o0[4 * c] * sw, o0[4 * c + 1] * sw, o0[4 * c + 2] * sw, o0[4 * c + 3] * sw};
        *(f32x4*)&co[wid][l][4 * c] = t;
    }
    __syncthreads();
    if (wid == 0) {
        #pragma unroll
        for (int rq = 0; rq < 4; ++rq) {
            f32x4 s = *(const f32x4*)&co[0][l][4 * rq];
            #pragma unroll
            for (int w2 = 1; w2 < 4; ++w2) {
                f32x4 t = *(const f32x4*)&co[w2][l][4 * rq];
                s.x += t.x; s.y += t.y; s.z += t.z; s.w += t.w;
            }
            u16x4 ov;
            ov.x = f2bf(s.x * inv); ov.y = f2bf(s.y * inv);
            ov.z = f2bf(s.z * inv); ov.w = f2bf(s.w * inv);
            *(u16x4*)(crow + 8 * rq + 4 * hi1) = ov;
        }
    }
    __syncthreads();
    // phase B: o1 (d = 32..63)
    #pragma unroll
    for (int c = 0; c < 4; ++c) {
        f32x4 t = {o1[4 * c] * sw, o1[4 * c + 1] * sw, o1[4 * c + 2] * sw, o1[4 * c + 3] * sw};
        *(f32x4*)&co[wid][l][4 * c] = t;
    }
    __syncthreads();
    if (wid == 0) {
        #pragma unroll
        for (int rq = 0; rq < 4; ++rq) {
            f32x4 s = *(const f32x4*)&co[0][l][4 * rq];
            #pragma unroll
            for (int w2 = 1; w2 < 4; ++w2) {
                f32x4 t = *(const f32x4*)&co[w2][l][4 * rq];
                s.x += t.x; s.y += t.y; s.z += t.z; s.w += t.w;
            }
            u16x4 ov;
            ov.x = f2bf(s.x * inv); ov.y = f2bf(s.y * inv);
            ov.z = f2bf(s.z * inv); ov.w = f2bf(s.w * inv);
            *(u16x4*)(crow + 32 + 8 * rq + 4 * hi1) = ov;
        }
    }
}

extern "C" void kernel_launch(void* const* d_in, const int* in_sizes, int n_in,
                              void* d_out, int out_size, void* d_ws, size_t ws_size,
                              hipStream_t stream)
{
    const float* x  = (const float*)d_in[0];
    const float* Wq = (const float*)d_in[1];
    const float* Wk = (const float*)d_in[2];
    const float* Wv = (const float*)d_in[3];
    const float* Wo = (const float*)d_in[4];
    const float* bo = (const float*)d_in[5];
    float* out = (float*)d_out;

    char* ws = (char*)d_ws;
    unsigned short* x_bf = (unsigned short*)(ws);                  // 8 MiB [4096][1024]
    unsigned short* WqT  = (unsigned short*)(ws + (8u << 20));     // 2 MiB
    unsigned short* WkT  = (unsigned short*)(ws + (10u << 20));    // 2 MiB
    unsigned short* WvT  = (unsigned short*)(ws + (12u << 20));    // 2 MiB
    unsigned short* WoT  = (unsigned short*)(ws + (14u << 20));    // 2 MiB
    unsigned short* QKV  = (unsigned short*)(ws + (16u << 20));    // 24 MiB: Q | K*scale | V^T
    unsigned short* ctx  = (unsigned short*)(ws + (40u << 20));    // 8 MiB [4096][1024]
    (void)in_sizes; (void)n_in; (void)out_size; (void)ws_size;

    cast_x<<<dim3((M_TOK * D_MODEL / 4 + 255) / 256), 256, 0, stream>>>(x, x_bf, M_TOK * D_MODEL / 4);
    transpose_cast4<<<dim3(32, 32, 4), 256, 0, stream>>>(Wq, Wk, Wv, Wo, WqT, WkT, WvT, WoT);

    gemm_bf16<<<dim3(M_TOK / BM, 3072 / BN), 256, 0, stream>>>(
        x_bf, WqT, QKV, nullptr, M_TOK, 3072, D_MODEL, 1);

    attn_fwd<<<dim3(T_SEQ / 32, BATCH * N_HEAD), 256, 0, stream>>>(QKV, ctx);

    gemm_bf16<<<dim3(M_TOK / BM, D_MODEL / BN), 256, 0, stream>>>(
        ctx, WoT, out, bo, M_TOK, D_MODEL, D_MODEL, 2);
}

// Round 9
// 211.120 us; speedup vs baseline: 1.3215x; 1.1798x over previous
//
#include <hip/hip_runtime.h>
#include <hip/hip_bf16.h>

typedef __attribute__((ext_vector_type(8))) short short8;
typedef __attribute__((ext_vector_type(4))) float f32x4;
typedef __attribute__((ext_vector_type(16))) float f32x16;
typedef __attribute__((ext_vector_type(4))) unsigned short u16x4;

#define D_MODEL 1024
#define N_HEAD 16
#define HEAD_DIM 64
#define T_SEQ 2048
#define BATCH 2
#define M_TOK (BATCH * T_SEQ) /* 4096 */
#define QKV_STRIDE ((size_t)M_TOK * D_MODEL) /* elems per Q/K/V buffer */

__device__ __forceinline__ unsigned short f2bf(float f) {
    union { float f; unsigned u; } v; v.f = f;
    unsigned r = (v.u + 0x7fffu + ((v.u >> 16) & 1u)) >> 16;  // RNE
    return (unsigned short)r;
}

__device__ __forceinline__ float exp2_fast(float x) {
    float r;
    asm("v_exp_f32 %0, %1" : "=v"(r) : "v"(x));   // 2^x
    return r;
}

__device__ __forceinline__ void load16_lds(const unsigned short* g, unsigned short* l) {
    __builtin_amdgcn_global_load_lds(
        (const __attribute__((address_space(1))) unsigned int*)(g),
        (__attribute__((address_space(3))) unsigned int*)(l),
        16, 0, 0);
}

// ---------------- cast x (f32 -> bf16), vectorized ----------------
__global__ __launch_bounds__(256) void cast_x(const float* __restrict__ in,
                                              unsigned short* __restrict__ out, int n4) {
    int i = blockIdx.x * 256 + threadIdx.x;
    if (i < n4) {
        float4 v = ((const float4*)in)[i];
        u16x4 o;
        o.x = f2bf(v.x); o.y = f2bf(v.y); o.z = f2bf(v.z); o.w = f2bf(v.w);
        ((u16x4*)out)[i] = o;
    }
}

// ---------------- transpose + cast all 4 weights [1024][1024] f32 -> bf16 T ----------------
__global__ __launch_bounds__(256) void transpose_cast4(
    const float* __restrict__ w0, const float* __restrict__ w1,
    const float* __restrict__ w2, const float* __restrict__ w3,
    unsigned short* __restrict__ o0, unsigned short* __restrict__ o1,
    unsigned short* __restrict__ o2, unsigned short* __restrict__ o3)
{
    __shared__ float tile[32][33];
    const float* in; unsigned short* outT;
    switch (blockIdx.z) {
        case 0: in = w0; outT = o0; break;
        case 1: in = w1; outT = o1; break;
        case 2: in = w2; outT = o2; break;
        default: in = w3; outT = o3; break;
    }
    const int R = 1024, C = 1024;
    const int r0 = blockIdx.x * 32, c0 = blockIdx.y * 32;
    const int tx = threadIdx.x & 31, ty = threadIdx.x >> 5;  // ty 0..7
    #pragma unroll
    for (int jj = 0; jj < 32; jj += 8)
        tile[ty + jj][tx] = in[(size_t)(r0 + ty + jj) * C + c0 + tx];
    __syncthreads();
    #pragma unroll
    for (int jj = 0; jj < 32; jj += 8)
        outT[(size_t)(c0 + ty + jj) * R + r0 + tx] = f2bf(tile[tx][ty + jj]);
}

// ---------------- 2-phase pipelined GEMM: C[M,N] = A[M,K] * Bt[N,K]^T ----------------
// 128x128 tile, BK=32, 4 waves, double-buffered LDS, stage(next) overlaps MFMA(cur).
// mode 1: scatter into QKV: Q raw; K scaled by 0.125*log2(e); V transposed [B,H,Dh,T]
// mode 2: f32 out[M,N] + bias[n]
#define BM 128
#define BN 128
#define BK 32
__global__ __launch_bounds__(256) void gemm_bf16(
    const unsigned short* __restrict__ A,
    const unsigned short* __restrict__ Bt,
    void* __restrict__ outp,
    const float* __restrict__ bias,
    int M, int N, int K, int mode)
{
    __shared__ unsigned short lds_a[2][BM * BK];  // 2 x 8 KiB
    __shared__ unsigned short lds_b[2][BN * BK];  // 2 x 8 KiB
    const int tid = threadIdx.x;
    const int w = tid >> 6, l = tid & 63, lo = l & 15, hi = l >> 4;
    const int wm = w >> 1, wn = w & 1;
    const size_t arow0 = (size_t)blockIdx.x * BM;
    const size_t brow0 = (size_t)blockIdx.y * BN;

    f32x4 acc[4][4];
    #pragma unroll
    for (int i = 0; i < 4; ++i)
        #pragma unroll
        for (int j = 0; j < 4; ++j)
            acc[i][j] = (f32x4){0.f, 0.f, 0.f, 0.f};

    const int ch0 = tid, ch1 = 256 + tid;
    const int r0c = ch0 >> 2, c0c = (ch0 & 3) * 8;
    const int r1c = ch1 >> 2, c1c = (ch1 & 3) * 8;
    const unsigned short* Ab0 = A + (arow0 + r0c) * K + c0c;
    const unsigned short* Ab1 = A + (arow0 + r1c) * K + c1c;
    const unsigned short* Bb0 = Bt + (brow0 + r0c) * K + c0c;
    const unsigned short* Bb1 = Bt + (brow0 + r1c) * K + c1c;
    const int woff0 = (0 * 256 + w * 64) * 8, woff1 = (1 * 256 + w * 64) * 8;

#define GSTAGE(BUF, KOFF)                                  \
    do {                                                   \
        load16_lds(Ab0 + (KOFF), lds_a[BUF] + woff0);      \
        load16_lds(Ab1 + (KOFF), lds_a[BUF] + woff1);      \
        load16_lds(Bb0 + (KOFF), lds_b[BUF] + woff0);      \
        load16_lds(Bb1 + (KOFF), lds_b[BUF] + woff1);      \
    } while (0)

    GSTAGE(0, 0);
    int cur = 0;
    for (int k0 = 0; k0 < K; k0 += BK) {
        __syncthreads();                       // drains in-flight stage (vmcnt0) + barrier
        if (k0 + BK < K) GSTAGE(cur ^ 1, k0 + BK);   // overlap next stage with current MFMAs
        short8 af[4], bfr[4];
        #pragma unroll
        for (int i = 0; i < 4; ++i)
            af[i] = *(const short8*)(lds_a[cur] + (wm * 64 + i * 16 + lo) * BK + 8 * hi);
        #pragma unroll
        for (int j = 0; j < 4; ++j)
            bfr[j] = *(const short8*)(lds_b[cur] + (wn * 64 + j * 16 + lo) * BK + 8 * hi);
        #pragma unroll
        for (int i = 0; i < 4; ++i)
            #pragma unroll
            for (int j = 0; j < 4; ++j)
                acc[i][j] = __builtin_amdgcn_mfma_f32_16x16x32_bf16(af[i], bfr[j], acc[i][j], 0, 0, 0);
        cur ^= 1;
    }
#undef GSTAGE

    const int m00 = (int)arow0 + wm * 64;
    const int n00 = (int)brow0 + wn * 64;
    if (mode == 1) {
        unsigned short* out = (unsigned short*)outp;
        #pragma unroll
        for (int i = 0; i < 4; ++i)
            #pragma unroll
            for (int j = 0; j < 4; ++j) {
                const int nbase = n00 + j * 16;
                const int qkv = nbase >> 10;          // block-uniform
                #pragma unroll
                for (int e = 0; e < 4; ++e) {
                    const int m = m00 + i * 16 + 4 * hi + e;
                    const int n = nbase + lo;
                    const int b = m >> 11, t = m & 2047;
                    const int h = (n >> 6) & 15, d = n & 63;
                    const int bh = (b << 4) + h;
                    float v = acc[i][j][e];
                    size_t off;
                    if (qkv == 0) {
                        off = ((size_t)bh * T_SEQ + t) * HEAD_DIM + d;
                    } else if (qkv == 1) {
                        v *= 0.18033688f;  // 1/sqrt(Dh) * log2(e): exp -> exp2 in attn
                        off = QKV_STRIDE + ((size_t)bh * T_SEQ + t) * HEAD_DIM + d;
                    } else {
                        off = 2 * QKV_STRIDE + ((size_t)bh * HEAD_DIM + d) * T_SEQ + t;  // V^T
                    }
                    out[off] = f2bf(v);
                }
            }
    } else {
        float* out = (float*)outp;
        #pragma unroll
        for (int i = 0; i < 4; ++i)
            #pragma unroll
            for (int j = 0; j < 4; ++j)
                #pragma unroll
                for (int e = 0; e < 4; ++e) {
                    const int m = m00 + i * 16 + 4 * hi + e;
                    const int n = n00 + j * 16 + lo;
                    out[(size_t)m * N + n] = acc[i][j][e] + bias[n];
                }
    }
}

// ---------------- causal flash attention: 4 waves x 32 q-rows, shared LDS K/V window ------
// Block covers 128 q-rows of one bh. Super-iteration si stages a 128-k window
// (K[128][64], V^T[64][128], chunk16 XOR-swizzled via pre-swizzled global source)
// double-buffered; each wave computes its 32x32 S^T/PV per 32-k block from LDS.
// Per-wave math identical to verified R8 kernel (swapped QK^T, in-reg softmax, O^T PV).
__global__ __launch_bounds__(256) void attn_fwd(
    const unsigned short* __restrict__ QKV,   // Q | K(pre-scaled by 0.125*log2e) | V^T
    unsigned short* __restrict__ ctx)
{
    const int qi = (int)(gridDim.x - 1 - blockIdx.x);  // longest-first, 0..15
    const int bh = blockIdx.y;
    const int b = bh >> 4, h = bh & 15;
    const int tid = threadIdx.x;
    const int wid = tid >> 6;
    const int l = tid & 63;
    const int l31 = l & 31, hi1 = l >> 5;
    const int q0w = qi * 128 + wid * 32;      // this wave's q-tile base
    const int q = q0w + l31;

    const unsigned short* Qb = QKV + (size_t)bh * T_SEQ * HEAD_DIM;
    const unsigned short* Kb = QKV + QKV_STRIDE + (size_t)bh * T_SEQ * HEAD_DIM;
    const unsigned short* Vb = QKV + 2 * QKV_STRIDE + (size_t)bh * HEAD_DIM * T_SEQ;

    __shared__ unsigned short kbuf[2][128 * 64];   // 2 x 16 KiB, row = 64 elems (8 chunk16)
    __shared__ unsigned short vbuf[2][64 * 128];   // 2 x 16 KiB, row = 128 elems (16 chunk16)

    short8 qf[4];
    #pragma unroll
    for (int st = 0; st < 4; ++st)
        qf[st] = *(const short8*)(Qb + (size_t)q * 64 + 16 * st + 8 * hi1);

    f32x16 o0, o1;
    #pragma unroll
    for (int r = 0; r < 16; ++r) { o0[r] = 0.f; o1[r] = 0.f; }
    float mrun = -3e38f, lsum = 0.f;

    // stage: linear LDS dest (wave-uniform base + lane*16), inverse-swizzled global src.
    // K chunk (row, c) holds src[row][c ^ (row&7)]; same for V (16 chunks/row, XOR low-3).
#define STAGE(B, SI)                                                                     \
    do {                                                                                 \
        _Pragma("unroll")                                                                \
        for (int it = 0; it < 4; ++it) {                                                 \
            const int D = it * 256 + tid;                                                \
            const int kr = D >> 3, kc = D & 7;                                           \
            load16_lds(Kb + (size_t)((SI) * 128 + kr) * 64 + ((kc ^ (kr & 7)) * 8),      \
                       &kbuf[B][(it * 256 + wid * 64) * 8]);                             \
            const int vr = D >> 4, vc = D & 15;                                          \
            load16_lds(Vb + (size_t)vr * T_SEQ + (SI) * 128 + ((vc ^ (vr & 7)) * 8),     \
                       &vbuf[B][(it * 256 + wid * 64) * 8]);                             \
        }                                                                                \
    } while (0)

    STAGE(0, 0);
    int cur = 0;
    for (int si = 0; si <= qi; ++si) {
        __syncthreads();                           // stage(si) done; prev buffer free
        if (si < qi) STAGE(cur ^ 1, si + 1);       // overlap with compute below
        #pragma unroll
        for (int kbl = 0; kbl < 4; ++kbl) {
            const int kbase = si * 128 + kbl * 32;
            if (kbase <= q0w) {
                // K fragments (swizzled read)
                short8 kf[4];
                #pragma unroll
                for (int st = 0; st < 4; ++st) {
                    const int r = kbl * 32 + l31;
                    const int cc = (2 * st + hi1) ^ (r & 7);
                    kf[st] = *(const short8*)&kbuf[cur][r * 64 + cc * 8];
                }
                f32x16 s_;
                #pragma unroll
                for (int r = 0; r < 16; ++r) s_[r] = 0.f;
                s_ = __builtin_amdgcn_mfma_f32_32x32x16_bf16(kf[0], qf[0], s_, 0, 0, 0);
                s_ = __builtin_amdgcn_mfma_f32_32x32x16_bf16(kf[1], qf[1], s_, 0, 0, 0);
                s_ = __builtin_amdgcn_mfma_f32_32x32x16_bf16(kf[2], qf[2], s_, 0, 0, 0);
                s_ = __builtin_amdgcn_mfma_f32_32x32x16_bf16(kf[3], qf[3], s_, 0, 0, 0);
                if (kbase == q0w) {   // diagonal block: mask k > q
                    #pragma unroll
                    for (int r = 0; r < 16; ++r)
                        if ((r & 3) + 8 * (r >> 2) + 4 * hi1 > l31) s_[r] = -3e38f;
                }
                float pm = s_[0];
                #pragma unroll
                for (int r = 1; r < 16; ++r) pm = fmaxf(pm, s_[r]);
                pm = fmaxf(pm, __shfl_xor(pm, 32));
                if (__any(pm > mrun + 8.0f)) {       // defer-max (T13)
                    const float mnew = fmaxf(mrun, pm);
                    const float sc = exp2_fast(mrun - mnew);
                    mrun = mnew;
                    lsum *= sc;
                    #pragma unroll
                    for (int r = 0; r < 16; ++r) { o0[r] *= sc; o1[r] *= sc; }
                }
                float p[16];
                #pragma unroll
                for (int r = 0; r < 16; ++r) p[r] = exp2_fast(s_[r] - mrun);
                float rs = (((p[0] + p[1]) + (p[2] + p[3])) + ((p[4] + p[5]) + (p[6] + p[7])))
                         + (((p[8] + p[9]) + (p[10] + p[11])) + ((p[12] + p[13]) + (p[14] + p[15])));
                rs += __shfl_xor(rs, 32);
                lsum += rs;
                unsigned c0, c1, c2, c3, c4, c5, c6, c7;
                asm volatile("v_cvt_pk_bf16_f32 %0, %1, %2" : "=v"(c0) : "v"(p[0]),  "v"(p[1]));
                asm volatile("v_cvt_pk_bf16_f32 %0, %1, %2" : "=v"(c1) : "v"(p[2]),  "v"(p[3]));
                asm volatile("v_cvt_pk_bf16_f32 %0, %1, %2" : "=v"(c2) : "v"(p[4]),  "v"(p[5]));
                asm volatile("v_cvt_pk_bf16_f32 %0, %1, %2" : "=v"(c3) : "v"(p[6]),  "v"(p[7]));
                asm volatile("v_cvt_pk_bf16_f32 %0, %1, %2" : "=v"(c4) : "v"(p[8]),  "v"(p[9]));
                asm volatile("v_cvt_pk_bf16_f32 %0, %1, %2" : "=v"(c5) : "v"(p[10]), "v"(p[11]));
                asm volatile("v_cvt_pk_bf16_f32 %0, %1, %2" : "=v"(c6) : "v"(p[12]), "v"(p[13]));
                asm volatile("v_cvt_pk_bf16_f32 %0, %1, %2" : "=v"(c7) : "v"(p[14]), "v"(p[15]));
                asm volatile("v_permlane32_swap_b32 %0, %1" : "+v"(c0), "+v"(c2));
                asm volatile("v_permlane32_swap_b32 %0, %1" : "+v"(c1), "+v"(c3));
                asm volatile("v_permlane32_swap_b32 %0, %1" : "+v"(c4), "+v"(c6));
                asm volatile("v_permlane32_swap_b32 %0, %1" : "+v"(c5), "+v"(c7));
                union { short8 v; unsigned u[4]; } pb0, pb1;
                pb0.u[0] = c0; pb0.u[1] = c1; pb0.u[2] = c2; pb0.u[3] = c3;
                pb1.u[0] = c4; pb1.u[1] = c5; pb1.u[2] = c6; pb1.u[3] = c7;
                // V^T fragments (swizzled read): rows d=l31, 32+l31
                const int d0 = l31, d1 = 32 + l31;
                const int cv00 = (kbl * 4 + 0 + hi1) ^ (d0 & 7);
                const int cv01 = (kbl * 4 + 2 + hi1) ^ (d0 & 7);
                const int cv10 = (kbl * 4 + 0 + hi1) ^ (d1 & 7);
                const int cv11 = (kbl * 4 + 2 + hi1) ^ (d1 & 7);
                const short8 v00 = *(const short8*)&vbuf[cur][d0 * 128 + cv00 * 8];
                const short8 v01 = *(const short8*)&vbuf[cur][d0 * 128 + cv01 * 8];
                const short8 v10 = *(const short8*)&vbuf[cur][d1 * 128 + cv10 * 8];
                const short8 v11 = *(const short8*)&vbuf[cur][d1 * 128 + cv11 * 8];
                o0 = __builtin_amdgcn_mfma_f32_32x32x16_bf16(v00, pb0.v, o0, 0, 0, 0);
                o0 = __builtin_amdgcn_mfma_f32_32x32x16_bf16(v01, pb1.v, o0, 0, 0, 0);
                o1 = __builtin_amdgcn_mfma_f32_32x32x16_bf16(v10, pb0.v, o1, 0, 0, 0);
                o1 = __builtin_amdgcn_mfma_f32_32x32x16_bf16(v11, pb1.v, o1, 0, 0, 0);
            }
        }
        cur ^= 1;
    }
#undef STAGE

    // epilogue: O^T: lane q = q0w + l31, d = (reg&3)+8*(reg>>2)+4*hi1 (+32 for o1)
    const float inv = 1.0f / lsum;
    unsigned short* crow = ctx + (size_t)(b * T_SEQ + q) * D_MODEL + h * 64;
    #pragma unroll
    for (int rq = 0; rq < 4; ++rq) {
        const int dd = 8 * rq + 4 * hi1;
        u16x4 ov;
        ov.x = f2bf(o0[4 * rq + 0] * inv);
        ov.y = f2bf(o0[4 * rq + 1] * inv);
        ov.z = f2bf(o0[4 * rq + 2] * inv);
        ov.w = f2bf(o0[4 * rq + 3] * inv);
        *(u16x4*)(crow + dd) = ov;
        u16x4 ov1;
        ov1.x = f2bf(o1[4 * rq + 0] * inv);
        ov1.y = f2bf(o1[4 * rq + 1] * inv);
        ov1.z = f2bf(o1[4 * rq + 2] * inv);
        ov1.w = f2bf(o1[4 * rq + 3] * inv);
        *(u16x4*)(crow + 32 + dd) = ov1;
    }
}

extern "C" void kernel_launch(void* const* d_in, const int* in_sizes, int n_in,
                              void* d_out, int out_size, void* d_ws, size_t ws_size,
                              hipStream_t stream)
{
    const float* x  = (const float*)d_in[0];
    const float* Wq = (const float*)d_in[1];
    const float* Wk = (const float*)d_in[2];
    const float* Wv = (const float*)d_in[3];
    const float* Wo = (const float*)d_in[4];
    const float* bo = (const float*)d_in[5];
    float* out = (float*)d_out;

    char* ws = (char*)d_ws;
    unsigned short* x_bf = (unsigned short*)(ws);                  // 8 MiB [4096][1024]
    unsigned short* WqT  = (unsigned short*)(ws + (8u << 20));     // 2 MiB
    unsigned short* WkT  = (unsigned short*)(ws + (10u << 20));    // 2 MiB
    unsigned short* WvT  = (unsigned short*)(ws + (12u << 20));    // 2 MiB
    unsigned short* WoT  = (unsigned short*)(ws + (14u << 20));    // 2 MiB
    unsigned short* QKV  = (unsigned short*)(ws + (16u << 20));    // 24 MiB: Q | K*scale | V^T
    unsigned short* ctx  = (unsigned short*)(ws + (40u << 20));    // 8 MiB [4096][1024]
    (void)in_sizes; (void)n_in; (void)out_size; (void)ws_size;

    cast_x<<<dim3((M_TOK * D_MODEL / 4 + 255) / 256), 256, 0, stream>>>(x, x_bf, M_TOK * D_MODEL / 4);
    transpose_cast4<<<dim3(32, 32, 4), 256, 0, stream>>>(Wq, Wk, Wv, Wo, WqT, WkT, WvT, WoT);

    gemm_bf16<<<dim3(M_TOK / BM, 3072 / BN), 256, 0, stream>>>(
        x_bf, WqT, QKV, nullptr, M_TOK, 3072, D_MODEL, 1);

    attn_fwd<<<dim3(T_SEQ / 128, BATCH * N_HEAD), 256, 0, stream>>>(QKV, ctx);

    gemm_bf16<<<dim3(M_TOK / BM, D_MODEL / BN), 256, 0, stream>>>(
        ctx, WoT, out, bo, M_TOK, D_MODEL, D_MODEL, 2);
}